// Round 3
// baseline (549.912 us; speedup 1.0000x reference)
//
#include <hip/hip_runtime.h>
#include <cstdint>

static constexpr int M = 16384;   // B*N rows
static constexpr int D = 768;     // feature dim
static constexpr int E = 32;      // code dim
static constexpr int K = 8192;    // codebook size

// ---------------- Kernel A: H1 = tanh(X @ W1 + b1)  [M,D]x[D,D] ----------------
// 128x128 tile, BK=16, 512 threads (8 waves -> 6 waves/SIMD at 3 blocks/CU),
// reg-prefetch double buffer, As padded to 132 (2-way writes), Bs group-swizzled.
__global__ __launch_bounds__(512, 6) void gemm1_tanh(
    const float* __restrict__ A, const float* __restrict__ B,
    const float* __restrict__ bias, float* __restrict__ C)
{
  constexpr int BK = 16;
  __shared__ float As[BK][132];
  __shared__ float Bs[BK][128];
  const int rowBase = blockIdx.x * 128;
  const int colBase = blockIdx.y * 128;
  const int t = threadIdx.x;
  const int tx = t & 15;        // 8-col group
  const int ty = t >> 4;        // 0..31, 4 rows each

  float acc[4][8];
#pragma unroll
  for (int i = 0; i < 4; ++i)
#pragma unroll
    for (int j = 0; j < 8; ++j) acc[i][j] = 0.f;

  // staging maps (1 float4 per thread per tile)
  const int ar = t >> 2, ak = (t & 3) * 4;   // A: 128 rows x 16 k
  const int bk = t >> 5, bn = (t & 31) * 4;  // B: 16 k x 128 n

  // Bs swizzle: float4-group g stored at g ^ (g>>3) (involution)
  const int g  = t & 31;
  const int pw = (g ^ (g >> 3)) * 4;
  const int gr0 = 2 * tx, gr1 = gr0 + 1;
  const int pr0 = (gr0 ^ (gr0 >> 3)) * 4;
  const int pr1 = (gr1 ^ (gr1 >> 3)) * 4;

  const float* Aptr = A + (size_t)(rowBase + ar) * D + ak;
  const float* Bptr = B + (size_t)bk * D + colBase + bn;

  float4 a0 = *(const float4*)Aptr;
  float4 b0 = *(const float4*)Bptr;

  for (int k0 = 0; k0 < D; k0 += BK) {
    As[ak + 0][ar] = a0.x; As[ak + 1][ar] = a0.y;
    As[ak + 2][ar] = a0.z; As[ak + 3][ar] = a0.w;
    *(float4*)&Bs[bk][pw] = b0;
    __syncthreads();
    if (k0 + BK < D) {
      a0 = *(const float4*)(Aptr + k0 + BK);
      b0 = *(const float4*)(Bptr + (size_t)(k0 + BK) * D);
    }
#pragma unroll
    for (int kk = 0; kk < BK; ++kk) {
      float4 av  = *(const float4*)&As[kk][ty * 4];
      float4 bv0 = *(const float4*)&Bs[kk][pr0];
      float4 bv1 = *(const float4*)&Bs[kk][pr1];
      const float a[4] = {av.x, av.y, av.z, av.w};
      const float b[8] = {bv0.x, bv0.y, bv0.z, bv0.w, bv1.x, bv1.y, bv1.z, bv1.w};
#pragma unroll
      for (int i = 0; i < 4; ++i)
#pragma unroll
        for (int j = 0; j < 8; ++j) acc[i][j] = fmaf(a[i], b[j], acc[i][j]);
    }
    __syncthreads();
  }

  float4 bv0 = *(const float4*)&bias[colBase + tx * 8];
  float4 bv1 = *(const float4*)&bias[colBase + tx * 8 + 4];
  const float bb[8] = {bv0.x, bv0.y, bv0.z, bv0.w, bv1.x, bv1.y, bv1.z, bv1.w};
#pragma unroll
  for (int i = 0; i < 4; ++i) {
    const int row = rowBase + ty * 4 + i;
    float o[8];
#pragma unroll
    for (int j = 0; j < 8; ++j) o[j] = tanhf(acc[i][j] + bb[j]);
    *(float4*)&C[(size_t)row * D + colBase + tx * 8]     = make_float4(o[0], o[1], o[2], o[3]);
    *(float4*)&C[(size_t)row * D + colBase + tx * 8 + 4] = make_float4(o[4], o[5], o[6], o[7]);
  }
}

// ---------------- Kernel B: Z = l2norm(H1 @ W2 + b2)  [M,D]x[D,E] ----------------
// 32 rows/block (512 blocks -> 2/CU); thread = (row, 4-col group); W2 chunk in LDS.
__global__ __launch_bounds__(256) void gemm2_norm(
    const float* __restrict__ H, const float* __restrict__ W2,
    const float* __restrict__ b2, float* __restrict__ Z)
{
  __shared__ float Hs[32 * 132];     // 32 rows x 128 k, padded
  __shared__ float W2s[128 * 32];    // k-chunk x 32
  const int t = threadIdx.x;
  const int rowBase = blockIdx.x * 32;
  const int rl = t >> 3;             // 0..31 local row
  const int n0 = (t & 7) * 4;        // col group: 0,4,...,28

  float acc[4] = {0.f, 0.f, 0.f, 0.f};

  for (int kc = 0; kc < D; kc += 128) {
    __syncthreads();
    for (int i = t; i < 32 * 32; i += 256) {
      const int r = i >> 5, gq = i & 31;
      *(float4*)&Hs[r * 132 + gq * 4] =
          *(const float4*)&H[(size_t)(rowBase + r) * D + kc + gq * 4];
    }
    for (int i = t; i < 1024; i += 256)
      *(float4*)&W2s[i * 4] = *(const float4*)&W2[(size_t)kc * E + i * 4];
    __syncthreads();
#pragma unroll 4
    for (int k4 = 0; k4 < 32; ++k4) {
      float4 hv = *(const float4*)&Hs[rl * 132 + k4 * 4];
      const float h[4] = {hv.x, hv.y, hv.z, hv.w};
#pragma unroll
      for (int j = 0; j < 4; ++j) {
        float4 w = *(const float4*)&W2s[(k4 * 4 + j) * E + n0];
        acc[0] = fmaf(h[j], w.x, acc[0]); acc[1] = fmaf(h[j], w.y, acc[1]);
        acc[2] = fmaf(h[j], w.z, acc[2]); acc[3] = fmaf(h[j], w.w, acc[3]);
      }
    }
  }

  float4 bb = *(const float4*)&b2[n0];
  acc[0] += bb.x; acc[1] += bb.y; acc[2] += bb.z; acc[3] += bb.w;
  float ss = acc[0] * acc[0];
  ss += acc[1] * acc[1]; ss += acc[2] * acc[2]; ss += acc[3] * acc[3];
  ss += __shfl_xor(ss, 1, 8);
  ss += __shfl_xor(ss, 2, 8);
  ss += __shfl_xor(ss, 4, 8);
  const float inv = 1.0f / fmaxf(sqrtf(ss), 1e-12f);
  float4 zv = make_float4(acc[0] * inv, acc[1] * inv, acc[2] * inv, acc[3] * inv);
  *(float4*)&Z[(size_t)(rowBase + rl) * E + n0] = zv;
}

// ---------------- Kernel CC: cc[k] = sum(codebook[k]^2) ----------------
__global__ __launch_bounds__(256) void cb_norms(const float* __restrict__ CB, float* __restrict__ cc)
{
  const int k = blockIdx.x * 256 + threadIdx.x;
  const float4* p = reinterpret_cast<const float4*>(CB + (size_t)k * E);
  float s = 0.f;
#pragma unroll
  for (int q = 0; q < 8; ++q) {
    float4 v = p[q];
    s += v.x * v.x; s += v.y * v.y; s += v.z * v.z; s += v.w * v.w;
  }
  cc[k] = s;
}

// ---------------- Kernel C: argmin distance + gather + STE + per-row loss ----------------
// 32 rows/block, 4 rows/thread (cl = 32 code lanes): 128 fma per 8 ds_read_b128.
__global__ __launch_bounds__(256, 2) void vq_argmin(
    const float* __restrict__ Z, const float* __restrict__ CB,
    const float* __restrict__ ccg, float* __restrict__ zq_out,
    float* __restrict__ idx_out, float* __restrict__ lossp)
{
  constexpr int CT = 256;       // codes per LDS tile
  constexpr int STRIDE = 36;    // padded floats per code
  __shared__ float cbs[CT * STRIDE];
  __shared__ float ccs[CT];

  const int rowBase = blockIdx.x * 32;
  const int t = threadIdx.x;
  const int cl = t & 31;        // code lane 0..31
  const int rs = t >> 5;        // row slot 0..7; rows rs + 8*j, j=0..3

  float4 z[4][8];
  float zz[4];
#pragma unroll
  for (int j = 0; j < 4; ++j) {
    const float4* p = (const float4*)(Z + (size_t)(rowBase + rs + 8 * j) * E);
#pragma unroll
    for (int q = 0; q < 8; ++q) z[j][q] = p[q];
    float s = 0.f;
#pragma unroll
    for (int q = 0; q < 8; ++q) {
      s += z[j][q].x * z[j][q].x; s += z[j][q].y * z[j][q].y;
      s += z[j][q].z * z[j][q].z; s += z[j][q].w * z[j][q].w;
    }
    zz[j] = s;
  }

  float best[4] = {3.4e38f, 3.4e38f, 3.4e38f, 3.4e38f};
  int bi[4] = {0, 0, 0, 0};

  for (int tb = 0; tb < K; tb += CT) {
    __syncthreads();
    const float4* src = (const float4*)(CB + (size_t)tb * E);
    for (int f = t; f < CT * 8; f += 256) {
      const int c = f >> 3, d4 = f & 7;
      *(float4*)&cbs[c * STRIDE + d4 * 4] = src[f];
    }
    ccs[t] = ccg[tb + t];
    __syncthreads();

    for (int c0 = 0; c0 < CT; c0 += 32) {
      const int c = c0 + cl;
      const float* cp = &cbs[c * STRIDE];
      float dot0 = 0.f, dot1 = 0.f, dot2 = 0.f, dot3 = 0.f;
#pragma unroll
      for (int q = 0; q < 8; ++q) {
        float4 v = *(const float4*)(cp + q * 4);
        dot0 = fmaf(v.x, z[0][q].x, dot0); dot0 = fmaf(v.y, z[0][q].y, dot0);
        dot0 = fmaf(v.z, z[0][q].z, dot0); dot0 = fmaf(v.w, z[0][q].w, dot0);
        dot1 = fmaf(v.x, z[1][q].x, dot1); dot1 = fmaf(v.y, z[1][q].y, dot1);
        dot1 = fmaf(v.z, z[1][q].z, dot1); dot1 = fmaf(v.w, z[1][q].w, dot1);
        dot2 = fmaf(v.x, z[2][q].x, dot2); dot2 = fmaf(v.y, z[2][q].y, dot2);
        dot2 = fmaf(v.z, z[2][q].z, dot2); dot2 = fmaf(v.w, z[2][q].w, dot2);
        dot3 = fmaf(v.x, z[3][q].x, dot3); dot3 = fmaf(v.y, z[3][q].y, dot3);
        dot3 = fmaf(v.z, z[3][q].z, dot3); dot3 = fmaf(v.w, z[3][q].w, dot3);
      }
      const float cv = ccs[c];
      const int kk = tb + c;
      const float d0 = (zz[0] + cv) - 2.0f * dot0;
      const float d1 = (zz[1] + cv) - 2.0f * dot1;
      const float d2 = (zz[2] + cv) - 2.0f * dot2;
      const float d3 = (zz[3] + cv) - 2.0f * dot3;
      if (d0 < best[0]) { best[0] = d0; bi[0] = kk; }
      if (d1 < best[1]) { best[1] = d1; bi[1] = kk; }
      if (d2 < best[2]) { best[2] = d2; bi[2] = kk; }
      if (d3 < best[3]) { best[3] = d3; bi[3] = kk; }
    }
  }

  // butterfly min-reduce over the 32 code lanes; tie -> lowest index
#pragma unroll
  for (int m = 16; m >= 1; m >>= 1) {
#pragma unroll
    for (int j = 0; j < 4; ++j) {
      const float ob = __shfl_xor(best[j], m, 32);
      const int   oi = __shfl_xor(bi[j],   m, 32);
      if (ob < best[j] || (ob == best[j] && oi < bi[j])) { best[j] = ob; bi[j] = oi; }
    }
  }

  // parallel epilogue: lane cl handles row j=cl>>3, quad q=cl&7 (static-index selects)
  const int jj = cl >> 3;
  const int qq = cl & 7;
  int bsel = bi[0];
#pragma unroll
  for (int j = 1; j < 4; ++j) if (jj == j) bsel = bi[j];
  float4 zsel = z[0][0];
#pragma unroll
  for (int j = 0; j < 4; ++j)
#pragma unroll
    for (int q = 0; q < 8; ++q)
      if (jj == j && qq == q) zsel = z[j][q];

  const int rw = rowBase + rs + 8 * jj;
  const float4 c4 = *(const float4*)&CB[(size_t)bsel * E + qq * 4];
  const float dx = c4.x - zsel.x, dy = c4.y - zsel.y;
  const float dz = c4.z - zsel.z, dw = c4.w - zsel.w;
  *(float4*)&zq_out[(size_t)rw * E + qq * 4] =
      make_float4(zsel.x + dx, zsel.y + dy, zsel.z + dz, zsel.w + dw);  // STE
  float ls = dx * dx;
  ls += dy * dy; ls += dz * dz; ls += dw * dw;
  ls += __shfl_xor(ls, 1, 8);
  ls += __shfl_xor(ls, 2, 8);
  ls += __shfl_xor(ls, 4, 8);
  if (qq == 0) {
    lossp[rw] = ls;
    idx_out[rw] = (float)bsel;
  }
}

// ---------------- Kernel D: loss = sum(lossp) / (M*E) ----------------
__global__ __launch_bounds__(256) void loss_reduce(const float* __restrict__ lossp, float* __restrict__ out)
{
  float s = 0.f;
  const float4* p = reinterpret_cast<const float4*>(lossp);
  for (int i = threadIdx.x; i < M / 4; i += 256) {
    float4 v = p[i];
    s += v.x + v.y + v.z + v.w;
  }
#pragma unroll
  for (int m = 32; m >= 1; m >>= 1) s += __shfl_xor(s, m, 64);
  __shared__ float red[4];
  if ((threadIdx.x & 63) == 0) red[threadIdx.x >> 6] = s;
  __syncthreads();
  if (threadIdx.x == 0)
    out[0] = (red[0] + red[1] + red[2] + red[3]) * (1.0f / (float)(M * E));
}

extern "C" void kernel_launch(void* const* d_in, const int* in_sizes, int n_in,
                              void* d_out, int out_size, void* d_ws, size_t ws_size,
                              hipStream_t stream)
{
  const float* X  = (const float*)d_in[0];  // [16,1024,768]
  const float* W1 = (const float*)d_in[1];  // [768,768]
  const float* b1 = (const float*)d_in[2];  // [768]
  const float* W2 = (const float*)d_in[3];  // [768,32]
  const float* b2 = (const float*)d_in[4];  // [32]
  const float* CB = (const float*)d_in[5];  // [8192,32]

  float* out  = (float*)d_out;
  float* zq   = out;                // 524288 floats
  float* loss = out + 524288;       // 1 float
  float* idxf = out + 524289;       // 16384 floats

  char* ws = (char*)d_ws;
  float* H1 = (float*)ws;                                        // M*D floats
  float* Z  = (float*)(ws + (size_t)M * D * sizeof(float));      // M*E floats
  float* cc = Z + (size_t)M * E;                                 // K floats
  float* lp = cc + K;                                            // M floats

  cb_norms<<<dim3(K / 256), 256, 0, stream>>>(CB, cc);           // independent; fills idle CUs
  gemm1_tanh<<<dim3(M / 128, D / 128), 512, 0, stream>>>(X, W1, b1, H1);
  gemm2_norm<<<dim3(M / 32), 256, 0, stream>>>(H1, W2, b2, Z);
  vq_argmin<<<dim3(M / 32), 256, 0, stream>>>(Z, CB, cc, zq, idxf, lp);
  loss_reduce<<<1, 256, 0, stream>>>(lp, loss);
}

// Round 4
// 375.743 us; speedup vs baseline: 1.4635x; 1.4635x over previous
//
#include <hip/hip_runtime.h>
#include <cstdint>

static constexpr int M = 16384;   // B*N rows
static constexpr int D = 768;     // feature dim
static constexpr int E = 32;      // code dim
static constexpr int K = 8192;    // codebook size

typedef _Float16 half8 __attribute__((ext_vector_type(8)));
typedef float f32x4 __attribute__((ext_vector_type(4)));

typedef __attribute__((address_space(1))) const uint32_t gu32;
typedef __attribute__((address_space(3))) uint32_t lu32;
__device__ __forceinline__ void g2l16(const void* g, void* l) {
  __builtin_amdgcn_global_load_lds((gu32*)g, (lu32*)l, 16, 0, 0);
}

// ---------------- Pre-pass: W1 [768k][768n] fp32 -> W1aT/W1bT [768n][768k] fp16 ----------------
// W1aT = fp16(64*w); W1bT = fp16((64*w - W1aT) * 4096)   (scales 2^6, 2^18)
__global__ __launch_bounds__(256) void split_w1t(const float* __restrict__ W1,
    _Float16* __restrict__ W1aT, _Float16* __restrict__ W1bT)
{
  __shared__ float tile[32][33];
  const int tx = threadIdx.x & 31, ty = threadIdx.x >> 5;  // ty 0..7
  const int kb = blockIdx.x * 32, nb = blockIdx.y * 32;
#pragma unroll
  for (int i = 0; i < 4; ++i)
    tile[ty * 4 + i][tx] = W1[(size_t)(kb + ty * 4 + i) * 768 + nb + tx];
  __syncthreads();
#pragma unroll
  for (int i = 0; i < 4; ++i) {
    const int n = nb + ty * 4 + i, k = kb + tx;
    const float v = tile[tx][ty * 4 + i] * 64.0f;
    const _Float16 h = (_Float16)v;
    W1aT[(size_t)n * 768 + k] = h;
    W1bT[(size_t)n * 768 + k] = (_Float16)((v - (float)h) * 4096.0f);
  }
}

// ---------------- Kernel A: H1 = tanh(X @ W1 + b1) via f16 MFMA split emulation ----------------
// 128x128 tile, BK=32, 4 waves (2x2 of 64x64), double-buffered LDS.
// A staged on the fly (fp32 -> hi/res fp16 via regs); B via global_load_lds width-16.
// accM holds a1*b1 (scale 2^6); accR holds a2*b1 + a1*b2 (scale 2^18).
__global__ __launch_bounds__(256, 2) void gemm1_mfma(
    const float* __restrict__ X, const _Float16* __restrict__ Bag,
    const _Float16* __restrict__ Bbg, const float* __restrict__ bias,
    float* __restrict__ C)
{
  __shared__ __align__(16) char smem[65536];
  constexpr int AaO = 0, AbO = 8192, BaO = 16384, BbO = 24576, BUF = 32768;

  const int t = threadIdx.x;
  const int lane = t & 63;
  const int wave = t >> 6;
  const int wm = wave >> 1, wn = wave & 1;
  const int rowBase = blockIdx.x * 128;
  const int colBase = blockIdx.y * 128;

  // staging: unit u in [0,512): row r=u>>2, 16B slot s=u&3 (8 elems at k=s*8)
  const int r0 = t >> 2, s0 = t & 3;
  const float* Xp0 = X + (size_t)(rowBase + r0) * D + s0 * 8;
  const float* Xp1 = X + (size_t)(rowBase + 64 + r0) * D + s0 * 8;
  const _Float16* BaP0 = Bag + (size_t)(colBase + r0) * D + s0 * 8;
  const _Float16* BaP1 = Bag + (size_t)(colBase + 64 + r0) * D + s0 * 8;
  const _Float16* BbP0 = Bbg + (size_t)(colBase + r0) * D + s0 * 8;
  const _Float16* BbP1 = Bbg + (size_t)(colBase + 64 + r0) * D + s0 * 8;
  const int ldsU0 = t * 16, ldsU1 = (256 + t) * 16;

  // fragment byte offsets within a tile: row*(64B) + kgroup*16B
  const int fragA = (wm * 64 + (lane & 15)) * 64 + (lane >> 4) * 16;
  const int fragB = (wn * 64 + (lane & 15)) * 64 + (lane >> 4) * 16;

  f32x4 accM[4][4], accR[4][4];
  const f32x4 z4 = {0.f, 0.f, 0.f, 0.f};
#pragma unroll
  for (int i = 0; i < 4; ++i)
#pragma unroll
    for (int j = 0; j < 4; ++j) { accM[i][j] = z4; accR[i][j] = z4; }

  auto cvtWrite = [&](char* buf, float4 pa, float4 pb, int off) {
    half8 hi, re;
    const float v[8] = {pa.x, pa.y, pa.z, pa.w, pb.x, pb.y, pb.z, pb.w};
#pragma unroll
    for (int e = 0; e < 8; ++e) {
      const _Float16 h = (_Float16)v[e];
      hi[e] = h;
      re[e] = (_Float16)((v[e] - (float)h) * 4096.0f);
    }
    *(half8*)(buf + AaO + off) = hi;
    *(half8*)(buf + AbO + off) = re;
  };
  auto stageB = [&](char* buf, int k0) {
    g2l16(BaP0 + k0, buf + BaO + ldsU0);
    g2l16(BaP1 + k0, buf + BaO + ldsU1);
    g2l16(BbP0 + k0, buf + BbO + ldsU0);
    g2l16(BbP1 + k0, buf + BbO + ldsU1);
  };

  { // prologue: stage ks=0 into buf0
    char* buf = smem;
    float4 p00 = *(const float4*)(Xp0);
    float4 p01 = *(const float4*)(Xp0 + 4);
    float4 p10 = *(const float4*)(Xp1);
    float4 p11 = *(const float4*)(Xp1 + 4);
    stageB(buf, 0);
    cvtWrite(buf, p00, p01, ldsU0);
    cvtWrite(buf, p10, p11, ldsU1);
    __syncthreads();
  }

  for (int ks = 0; ks < 24; ++ks) {
    char* bufc = smem + (ks & 1) * BUF;
    char* bufn = smem + ((ks + 1) & 1) * BUF;
    float4 p00, p01, p10, p11;
    const bool pre = (ks < 23);
    if (pre) {
      const int k1 = (ks + 1) * 32;
      p00 = *(const float4*)(Xp0 + k1);
      p01 = *(const float4*)(Xp0 + k1 + 4);
      p10 = *(const float4*)(Xp1 + k1);
      p11 = *(const float4*)(Xp1 + k1 + 4);
      stageB(bufn, k1);
    }
    half8 bAv[4], bBv[4];
#pragma unroll
    for (int fn = 0; fn < 4; ++fn) {
      bAv[fn] = *(const half8*)(bufc + BaO + fragB + fn * 1024);
      bBv[fn] = *(const half8*)(bufc + BbO + fragB + fn * 1024);
    }
#pragma unroll
    for (int fm = 0; fm < 4; ++fm) {
      half8 aA = *(const half8*)(bufc + AaO + fragA + fm * 1024);
      half8 aB = *(const half8*)(bufc + AbO + fragA + fm * 1024);
#pragma unroll
      for (int fn = 0; fn < 4; ++fn) {
        accM[fm][fn] = __builtin_amdgcn_mfma_f32_16x16x32_f16(aA, bAv[fn], accM[fm][fn], 0, 0, 0);
        accR[fm][fn] = __builtin_amdgcn_mfma_f32_16x16x32_f16(aB, bAv[fn], accR[fm][fn], 0, 0, 0);
        accR[fm][fn] = __builtin_amdgcn_mfma_f32_16x16x32_f16(aA, bBv[fn], accR[fm][fn], 0, 0, 0);
      }
    }
    if (pre) {
      cvtWrite(bufn, p00, p01, ldsU0);
      cvtWrite(bufn, p10, p11, ldsU1);
    }
    __syncthreads();
  }

  // epilogue: C[m][n] with m = (lane>>4)*4 + reg, n = lane&15 within fragment
#pragma unroll
  for (int fm = 0; fm < 4; ++fm) {
    const int mb = rowBase + wm * 64 + fm * 16 + (lane >> 4) * 4;
#pragma unroll
    for (int fn = 0; fn < 4; ++fn) {
      const int n = colBase + wn * 64 + fn * 16 + (lane & 15);
      const float bv = bias[n];
#pragma unroll
      for (int r = 0; r < 4; ++r) {
        const float val = accM[fm][fn][r] * 0.015625f
                        + accR[fm][fn][r] * 3.814697265625e-6f + bv;
        C[(size_t)(mb + r) * D + n] = tanhf(val);
      }
    }
  }
}

// ---------------- Kernel B: Z = l2norm(H1 @ W2 + b2)  [M,D]x[D,E] ----------------
__global__ __launch_bounds__(256) void gemm2_norm(
    const float* __restrict__ H, const float* __restrict__ W2,
    const float* __restrict__ b2, float* __restrict__ Z)
{
  __shared__ float Hs[32 * 132];
  __shared__ float W2s[128 * 32];
  const int t = threadIdx.x;
  const int rowBase = blockIdx.x * 32;
  const int rl = t >> 3;
  const int n0 = (t & 7) * 4;

  float acc[4] = {0.f, 0.f, 0.f, 0.f};

  for (int kc = 0; kc < D; kc += 128) {
    __syncthreads();
    for (int i = t; i < 32 * 32; i += 256) {
      const int r = i >> 5, gq = i & 31;
      *(float4*)&Hs[r * 132 + gq * 4] =
          *(const float4*)&H[(size_t)(rowBase + r) * D + kc + gq * 4];
    }
    for (int i = t; i < 1024; i += 256)
      *(float4*)&W2s[i * 4] = *(const float4*)&W2[(size_t)kc * E + i * 4];
    __syncthreads();
#pragma unroll 4
    for (int k4 = 0; k4 < 32; ++k4) {
      float4 hv = *(const float4*)&Hs[rl * 132 + k4 * 4];
      const float h[4] = {hv.x, hv.y, hv.z, hv.w};
#pragma unroll
      for (int j = 0; j < 4; ++j) {
        float4 w = *(const float4*)&W2s[(k4 * 4 + j) * E + n0];
        acc[0] = fmaf(h[j], w.x, acc[0]); acc[1] = fmaf(h[j], w.y, acc[1]);
        acc[2] = fmaf(h[j], w.z, acc[2]); acc[3] = fmaf(h[j], w.w, acc[3]);
      }
    }
  }

  float4 bb = *(const float4*)&b2[n0];
  acc[0] += bb.x; acc[1] += bb.y; acc[2] += bb.z; acc[3] += bb.w;
  float ss = acc[0] * acc[0];
  ss += acc[1] * acc[1]; ss += acc[2] * acc[2]; ss += acc[3] * acc[3];
  ss += __shfl_xor(ss, 1, 8);
  ss += __shfl_xor(ss, 2, 8);
  ss += __shfl_xor(ss, 4, 8);
  const float inv = 1.0f / fmaxf(sqrtf(ss), 1e-12f);
  float4 zv = make_float4(acc[0] * inv, acc[1] * inv, acc[2] * inv, acc[3] * inv);
  *(float4*)&Z[(size_t)(rowBase + rl) * E + n0] = zv;
}

// ---------------- Kernel CC: cc[k] = sum(codebook[k]^2) ----------------
__global__ __launch_bounds__(256) void cb_norms(const float* __restrict__ CB, float* __restrict__ cc)
{
  const int k = blockIdx.x * 256 + threadIdx.x;
  const float4* p = reinterpret_cast<const float4*>(CB + (size_t)k * E);
  float s = 0.f;
#pragma unroll
  for (int q = 0; q < 8; ++q) {
    float4 v = p[q];
    s += v.x * v.x; s += v.y * v.y; s += v.z * v.z; s += v.w * v.w;
  }
  cc[k] = s;
}

// ---------------- Kernel C: argmin distance + gather + STE + per-row loss ----------------
__global__ __launch_bounds__(256, 2) void vq_argmin(
    const float* __restrict__ Z, const float* __restrict__ CB,
    const float* __restrict__ ccg, float* __restrict__ zq_out,
    float* __restrict__ idx_out, float* __restrict__ lossp)
{
  constexpr int CT = 256;
  constexpr int STRIDE = 36;
  __shared__ float cbs[CT * STRIDE];
  __shared__ float ccs[CT];

  const int rowBase = blockIdx.x * 32;
  const int t = threadIdx.x;
  const int cl = t & 31;
  const int rs = t >> 5;

  float4 z[4][8];
  float zz[4];
#pragma unroll
  for (int j = 0; j < 4; ++j) {
    const float4* p = (const float4*)(Z + (size_t)(rowBase + rs + 8 * j) * E);
#pragma unroll
    for (int q = 0; q < 8; ++q) z[j][q] = p[q];
    float s = 0.f;
#pragma unroll
    for (int q = 0; q < 8; ++q) {
      s += z[j][q].x * z[j][q].x; s += z[j][q].y * z[j][q].y;
      s += z[j][q].z * z[j][q].z; s += z[j][q].w * z[j][q].w;
    }
    zz[j] = s;
  }

  float best[4] = {3.4e38f, 3.4e38f, 3.4e38f, 3.4e38f};
  int bi[4] = {0, 0, 0, 0};

  for (int tb = 0; tb < K; tb += CT) {
    __syncthreads();
    const float4* src = (const float4*)(CB + (size_t)tb * E);
    for (int f = t; f < CT * 8; f += 256) {
      const int c = f >> 3, d4 = f & 7;
      *(float4*)&cbs[c * STRIDE + d4 * 4] = src[f];
    }
    ccs[t] = ccg[tb + t];
    __syncthreads();

    for (int c0 = 0; c0 < CT; c0 += 32) {
      const int c = c0 + cl;
      const float* cp = &cbs[c * STRIDE];
      float dot0 = 0.f, dot1 = 0.f, dot2 = 0.f, dot3 = 0.f;
#pragma unroll
      for (int q = 0; q < 8; ++q) {
        float4 v = *(const float4*)(cp + q * 4);
        dot0 = fmaf(v.x, z[0][q].x, dot0); dot0 = fmaf(v.y, z[0][q].y, dot0);
        dot0 = fmaf(v.z, z[0][q].z, dot0); dot0 = fmaf(v.w, z[0][q].w, dot0);
        dot1 = fmaf(v.x, z[1][q].x, dot1); dot1 = fmaf(v.y, z[1][q].y, dot1);
        dot1 = fmaf(v.z, z[1][q].z, dot1); dot1 = fmaf(v.w, z[1][q].w, dot1);
        dot2 = fmaf(v.x, z[2][q].x, dot2); dot2 = fmaf(v.y, z[2][q].y, dot2);
        dot2 = fmaf(v.z, z[2][q].z, dot2); dot2 = fmaf(v.w, z[2][q].w, dot2);
        dot3 = fmaf(v.x, z[3][q].x, dot3); dot3 = fmaf(v.y, z[3][q].y, dot3);
        dot3 = fmaf(v.z, z[3][q].z, dot3); dot3 = fmaf(v.w, z[3][q].w, dot3);
      }
      const float cv = ccs[c];
      const int kk = tb + c;
      const float d0 = (zz[0] + cv) - 2.0f * dot0;
      const float d1 = (zz[1] + cv) - 2.0f * dot1;
      const float d2 = (zz[2] + cv) - 2.0f * dot2;
      const float d3 = (zz[3] + cv) - 2.0f * dot3;
      if (d0 < best[0]) { best[0] = d0; bi[0] = kk; }
      if (d1 < best[1]) { best[1] = d1; bi[1] = kk; }
      if (d2 < best[2]) { best[2] = d2; bi[2] = kk; }
      if (d3 < best[3]) { best[3] = d3; bi[3] = kk; }
    }
  }

#pragma unroll
  for (int m = 16; m >= 1; m >>= 1) {
#pragma unroll
    for (int j = 0; j < 4; ++j) {
      const float ob = __shfl_xor(best[j], m, 32);
      const int   oi = __shfl_xor(bi[j],   m, 32);
      if (ob < best[j] || (ob == best[j] && oi < bi[j])) { best[j] = ob; bi[j] = oi; }
    }
  }

  const int jj = cl >> 3;
  const int qq = cl & 7;
  int bsel = bi[0];
#pragma unroll
  for (int j = 1; j < 4; ++j) if (jj == j) bsel = bi[j];
  float4 zsel = z[0][0];
#pragma unroll
  for (int j = 0; j < 4; ++j)
#pragma unroll
    for (int q = 0; q < 8; ++q)
      if (jj == j && qq == q) zsel = z[j][q];

  const int rw = rowBase + rs + 8 * jj;
  const float4 c4 = *(const float4*)&CB[(size_t)bsel * E + qq * 4];
  const float dx = c4.x - zsel.x, dy = c4.y - zsel.y;
  const float dz = c4.z - zsel.z, dw = c4.w - zsel.w;
  *(float4*)&zq_out[(size_t)rw * E + qq * 4] =
      make_float4(zsel.x + dx, zsel.y + dy, zsel.z + dz, zsel.w + dw);
  float ls = dx * dx;
  ls += dy * dy; ls += dz * dz; ls += dw * dw;
  ls += __shfl_xor(ls, 1, 8);
  ls += __shfl_xor(ls, 2, 8);
  ls += __shfl_xor(ls, 4, 8);
  if (qq == 0) {
    lossp[rw] = ls;
    idx_out[rw] = (float)bsel;
  }
}

// ---------------- Kernel D: loss = sum(lossp) / (M*E) ----------------
__global__ __launch_bounds__(256) void loss_reduce(const float* __restrict__ lossp, float* __restrict__ out)
{
  float s = 0.f;
  const float4* p = reinterpret_cast<const float4*>(lossp);
  for (int i = threadIdx.x; i < M / 4; i += 256) {
    float4 v = p[i];
    s += v.x + v.y + v.z + v.w;
  }
#pragma unroll
  for (int m = 32; m >= 1; m >>= 1) s += __shfl_xor(s, m, 64);
  __shared__ float red[4];
  if ((threadIdx.x & 63) == 0) red[threadIdx.x >> 6] = s;
  __syncthreads();
  if (threadIdx.x == 0)
    out[0] = (red[0] + red[1] + red[2] + red[3]) * (1.0f / (float)(M * E));
}

extern "C" void kernel_launch(void* const* d_in, const int* in_sizes, int n_in,
                              void* d_out, int out_size, void* d_ws, size_t ws_size,
                              hipStream_t stream)
{
  const float* X  = (const float*)d_in[0];
  const float* W1 = (const float*)d_in[1];
  const float* b1 = (const float*)d_in[2];
  const float* W2 = (const float*)d_in[3];
  const float* b2 = (const float*)d_in[4];
  const float* CB = (const float*)d_in[5];

  float* out  = (float*)d_out;
  float* zq   = out;
  float* loss = out + 524288;
  float* idxf = out + 524289;

  char* ws = (char*)d_ws;
  float* H1 = (float*)ws;                                  // 48 MB
  float* Z  = (float*)(ws + (size_t)M * D * 4);            // 2 MB
  float* cc = Z + (size_t)M * E;                           // 32 KB
  float* lp = cc + K;                                      // 64 KB
  _Float16* W1aT = (_Float16*)(lp + M);                    // 1.125 MB
  _Float16* W1bT = W1aT + (size_t)D * D;                   // 1.125 MB

  split_w1t<<<dim3(D / 32, D / 32), 256, 0, stream>>>(W1, W1aT, W1bT);
  cb_norms<<<dim3(K / 256), 256, 0, stream>>>(CB, cc);
  gemm1_mfma<<<dim3(M / 128, D / 128), 256, 0, stream>>>(X, W1aT, W1bT, b1, H1);
  gemm2_norm<<<dim3(M / 32), 256, 0, stream>>>(H1, W2, b2, Z);
  vq_argmin<<<dim3(M / 32), 256, 0, stream>>>(Z, CB, cc, zq, idxf, lp);
  loss_reduce<<<1, 256, 0, stream>>>(lp, loss);
}

// Round 5
// 265.083 us; speedup vs baseline: 2.0745x; 1.4175x over previous
//
#include <hip/hip_runtime.h>
#include <cstdint>

static constexpr int M = 16384;   // B*N rows
static constexpr int D = 768;     // feature dim
static constexpr int E = 32;      // code dim
static constexpr int K = 8192;    // codebook size

typedef _Float16 half8 __attribute__((ext_vector_type(8)));
typedef float f32x4 __attribute__((ext_vector_type(4)));

typedef __attribute__((address_space(1))) const uint32_t gu32;
typedef __attribute__((address_space(3))) uint32_t lu32;
__device__ __forceinline__ void g2l16(const void* g, void* l) {
  __builtin_amdgcn_global_load_lds((gu32*)g, (lu32*)l, 16, 0, 0);
}

// ---------------- Pre-pass: W1 [768k][768n] fp32 -> W1aT/W1bT [768n][768k] fp16 ----------------
__global__ __launch_bounds__(256) void split_w1t(const float* __restrict__ W1,
    _Float16* __restrict__ W1aT, _Float16* __restrict__ W1bT)
{
  __shared__ float tile[32][33];
  const int tx = threadIdx.x & 31, ty = threadIdx.x >> 5;
  const int kb = blockIdx.x * 32, nb = blockIdx.y * 32;
#pragma unroll
  for (int i = 0; i < 4; ++i)
    tile[ty * 4 + i][tx] = W1[(size_t)(kb + ty * 4 + i) * 768 + nb + tx];
  __syncthreads();
#pragma unroll
  for (int i = 0; i < 4; ++i) {
    const int n = nb + ty * 4 + i, k = kb + tx;
    const float v = tile[tx][ty * 4 + i] * 64.0f;
    const _Float16 h = (_Float16)v;
    W1aT[(size_t)n * 768 + k] = h;
    W1bT[(size_t)n * 768 + k] = (_Float16)((v - (float)h) * 4096.0f);
  }
}

// ---------------- Pre-pass: codebook -> cc norms + f16 hi/res split ----------------
__global__ __launch_bounds__(256) void cb_prep(const float* __restrict__ CB,
    float* __restrict__ cc, _Float16* __restrict__ CBh, _Float16* __restrict__ CBr)
{
  const int k = blockIdx.x * 256 + threadIdx.x;
  const float4* p = (const float4*)(CB + (size_t)k * E);
  _Float16 hb[32], rb[32];
  float s = 0.f;
#pragma unroll
  for (int q = 0; q < 8; ++q) {
    float4 v = p[q];
    const float e[4] = {v.x, v.y, v.z, v.w};
#pragma unroll
    for (int j = 0; j < 4; ++j) {
      s += e[j] * e[j];
      const _Float16 h = (_Float16)e[j];
      hb[q * 4 + j] = h;
      rb[q * 4 + j] = (_Float16)((e[j] - (float)h) * 4096.0f);
    }
  }
  cc[k] = s;
#pragma unroll
  for (int q = 0; q < 4; ++q) {
    *(half8*)(CBh + (size_t)k * E + q * 8) = *(half8*)&hb[q * 8];
    *(half8*)(CBr + (size_t)k * E + q * 8) = *(half8*)&rb[q * 8];
  }
}

// ---------------- Kernel A: H1 = tanh(X @ W1 + b1) via f16 MFMA split emulation ----------------
__global__ __launch_bounds__(256, 2) void gemm1_mfma(
    const float* __restrict__ X, const _Float16* __restrict__ Bag,
    const _Float16* __restrict__ Bbg, const float* __restrict__ bias,
    float* __restrict__ C)
{
  __shared__ __align__(16) char smem[65536];
  constexpr int AaO = 0, AbO = 8192, BaO = 16384, BbO = 24576, BUF = 32768;

  const int t = threadIdx.x;
  const int lane = t & 63;
  const int wave = t >> 6;
  const int wm = wave >> 1, wn = wave & 1;
  const int rowBase = blockIdx.x * 128;
  const int colBase = blockIdx.y * 128;

  const int r0 = t >> 2, s0 = t & 3;
  const float* Xp0 = X + (size_t)(rowBase + r0) * D + s0 * 8;
  const float* Xp1 = X + (size_t)(rowBase + 64 + r0) * D + s0 * 8;
  const _Float16* BaP0 = Bag + (size_t)(colBase + r0) * D + s0 * 8;
  const _Float16* BaP1 = Bag + (size_t)(colBase + 64 + r0) * D + s0 * 8;
  const _Float16* BbP0 = Bbg + (size_t)(colBase + r0) * D + s0 * 8;
  const _Float16* BbP1 = Bbg + (size_t)(colBase + 64 + r0) * D + s0 * 8;
  const int ldsU0 = t * 16, ldsU1 = (256 + t) * 16;

  const int fragA = (wm * 64 + (lane & 15)) * 64 + (lane >> 4) * 16;
  const int fragB = (wn * 64 + (lane & 15)) * 64 + (lane >> 4) * 16;

  f32x4 accM[4][4], accR[4][4];
  const f32x4 z4 = {0.f, 0.f, 0.f, 0.f};
#pragma unroll
  for (int i = 0; i < 4; ++i)
#pragma unroll
    for (int j = 0; j < 4; ++j) { accM[i][j] = z4; accR[i][j] = z4; }

  auto cvtWrite = [&](char* buf, float4 pa, float4 pb, int off) {
    half8 hi, re;
    const float v[8] = {pa.x, pa.y, pa.z, pa.w, pb.x, pb.y, pb.z, pb.w};
#pragma unroll
    for (int e = 0; e < 8; ++e) {
      const _Float16 h = (_Float16)v[e];
      hi[e] = h;
      re[e] = (_Float16)((v[e] - (float)h) * 4096.0f);
    }
    *(half8*)(buf + AaO + off) = hi;
    *(half8*)(buf + AbO + off) = re;
  };
  auto stageB = [&](char* buf, int k0) {
    g2l16(BaP0 + k0, buf + BaO + ldsU0);
    g2l16(BaP1 + k0, buf + BaO + ldsU1);
    g2l16(BbP0 + k0, buf + BbO + ldsU0);
    g2l16(BbP1 + k0, buf + BbO + ldsU1);
  };

  {
    char* buf = smem;
    float4 p00 = *(const float4*)(Xp0);
    float4 p01 = *(const float4*)(Xp0 + 4);
    float4 p10 = *(const float4*)(Xp1);
    float4 p11 = *(const float4*)(Xp1 + 4);
    stageB(buf, 0);
    cvtWrite(buf, p00, p01, ldsU0);
    cvtWrite(buf, p10, p11, ldsU1);
    __syncthreads();
  }

  for (int ks = 0; ks < 24; ++ks) {
    char* bufc = smem + (ks & 1) * BUF;
    char* bufn = smem + ((ks + 1) & 1) * BUF;
    float4 p00, p01, p10, p11;
    const bool pre = (ks < 23);
    if (pre) {
      const int k1 = (ks + 1) * 32;
      p00 = *(const float4*)(Xp0 + k1);
      p01 = *(const float4*)(Xp0 + k1 + 4);
      p10 = *(const float4*)(Xp1 + k1);
      p11 = *(const float4*)(Xp1 + k1 + 4);
      stageB(bufn, k1);
    }
    half8 bAv[4], bBv[4];
#pragma unroll
    for (int fn = 0; fn < 4; ++fn) {
      bAv[fn] = *(const half8*)(bufc + BaO + fragB + fn * 1024);
      bBv[fn] = *(const half8*)(bufc + BbO + fragB + fn * 1024);
    }
#pragma unroll
    for (int fm = 0; fm < 4; ++fm) {
      half8 aA = *(const half8*)(bufc + AaO + fragA + fm * 1024);
      half8 aB = *(const half8*)(bufc + AbO + fragA + fm * 1024);
#pragma unroll
      for (int fn = 0; fn < 4; ++fn) {
        accM[fm][fn] = __builtin_amdgcn_mfma_f32_16x16x32_f16(aA, bAv[fn], accM[fm][fn], 0, 0, 0);
        accR[fm][fn] = __builtin_amdgcn_mfma_f32_16x16x32_f16(aB, bAv[fn], accR[fm][fn], 0, 0, 0);
        accR[fm][fn] = __builtin_amdgcn_mfma_f32_16x16x32_f16(aA, bBv[fn], accR[fm][fn], 0, 0, 0);
      }
    }
    if (pre) {
      cvtWrite(bufn, p00, p01, ldsU0);
      cvtWrite(bufn, p10, p11, ldsU1);
    }
    __syncthreads();
  }

#pragma unroll
  for (int fm = 0; fm < 4; ++fm) {
    const int mb = rowBase + wm * 64 + fm * 16 + (lane >> 4) * 4;
#pragma unroll
    for (int fn = 0; fn < 4; ++fn) {
      const int n = colBase + wn * 64 + fn * 16 + (lane & 15);
      const float bv = bias[n];
#pragma unroll
      for (int r = 0; r < 4; ++r) {
        const float val = accM[fm][fn][r] * 0.015625f
                        + accR[fm][fn][r] * 3.814697265625e-6f + bv;
        C[(size_t)(mb + r) * D + n] = tanhf(val);
      }
    }
  }
}

// ---------------- Kernel B: Z = l2norm(H1 @ W2 + b2)  [M,D]x[D,E] ----------------
__global__ __launch_bounds__(256) void gemm2_norm(
    const float* __restrict__ H, const float* __restrict__ W2,
    const float* __restrict__ b2, float* __restrict__ Z)
{
  __shared__ float Hs[32 * 132];
  __shared__ float W2s[128 * 32];
  const int t = threadIdx.x;
  const int rowBase = blockIdx.x * 32;
  const int rl = t >> 3;
  const int n0 = (t & 7) * 4;

  float acc[4] = {0.f, 0.f, 0.f, 0.f};

  for (int kc = 0; kc < D; kc += 128) {
    __syncthreads();
    for (int i = t; i < 32 * 32; i += 256) {
      const int r = i >> 5, gq = i & 31;
      *(float4*)&Hs[r * 132 + gq * 4] =
          *(const float4*)&H[(size_t)(rowBase + r) * D + kc + gq * 4];
    }
    for (int i = t; i < 1024; i += 256)
      *(float4*)&W2s[i * 4] = *(const float4*)&W2[(size_t)kc * E + i * 4];
    __syncthreads();
#pragma unroll 4
    for (int k4 = 0; k4 < 32; ++k4) {
      float4 hv = *(const float4*)&Hs[rl * 132 + k4 * 4];
      const float h[4] = {hv.x, hv.y, hv.z, hv.w};
#pragma unroll
      for (int j = 0; j < 4; ++j) {
        float4 w = *(const float4*)&W2s[(k4 * 4 + j) * E + n0];
        acc[0] = fmaf(h[j], w.x, acc[0]); acc[1] = fmaf(h[j], w.y, acc[1]);
        acc[2] = fmaf(h[j], w.z, acc[2]); acc[3] = fmaf(h[j], w.w, acc[3]);
      }
    }
  }

  float4 bb = *(const float4*)&b2[n0];
  acc[0] += bb.x; acc[1] += bb.y; acc[2] += bb.z; acc[3] += bb.w;
  float ss = acc[0] * acc[0];
  ss += acc[1] * acc[1]; ss += acc[2] * acc[2]; ss += acc[3] * acc[3];
  ss += __shfl_xor(ss, 1, 8);
  ss += __shfl_xor(ss, 2, 8);
  ss += __shfl_xor(ss, 4, 8);
  const float inv = 1.0f / fmaxf(sqrtf(ss), 1e-12f);
  float4 zv = make_float4(acc[0] * inv, acc[1] * inv, acc[2] * inv, acc[3] * inv);
  *(float4*)&Z[(size_t)(rowBase + rl) * E + n0] = zv;
}

// ---------------- Kernel C: VQ argmin via MFMA + gather + STE + per-row loss ----------------
// 64 rows/block, 8 waves: wave = (row-half mh, code-quarter cq). No LDS/barriers
// in the main loop; 1KB LDS for the 4-way cross-wave merge.
__global__ __launch_bounds__(512) void vq_mfma(
    const float* __restrict__ Z, const float* __restrict__ CB,
    const _Float16* __restrict__ CBh, const _Float16* __restrict__ CBr,
    const float* __restrict__ ccg, float* __restrict__ zq_out,
    float* __restrict__ idx_out, float* __restrict__ lossp)
{
  __shared__ float bDs[64][4];
  __shared__ int   bIs[64][4];

  const int t = threadIdx.x;
  const int lane = t & 63, wave = t >> 6;
  const int mh = wave & 1;        // row half: rows mh*32 .. +32
  const int cq = wave >> 1;       // code quarter: codes cq*2048 .. +2048
  const int rowBase = blockIdx.x * 64;
  const int col = lane & 15, kg = lane >> 4;

  // A-frags: z hi/res for 2 m-tiles (row = col-lane, k = kg*8..+8)
  half8 zh[2], zr[2];
#pragma unroll
  for (int mt = 0; mt < 2; ++mt) {
    const float* zp = Z + (size_t)(rowBase + mh * 32 + mt * 16 + col) * E + kg * 8;
    const float4 a = *(const float4*)zp;
    const float4 b = *(const float4*)(zp + 4);
    const float v[8] = {a.x, a.y, a.z, a.w, b.x, b.y, b.z, b.w};
#pragma unroll
    for (int e = 0; e < 8; ++e) {
      const _Float16 h = (_Float16)v[e];
      zh[mt][e] = h;
      zr[mt][e] = (_Float16)((v[e] - (float)h) * 4096.0f);
    }
  }

  const f32x4 zero4 = {0.f, 0.f, 0.f, 0.f};
  float best[2][4];
  int bi[2][4];
#pragma unroll
  for (int mt = 0; mt < 2; ++mt)
#pragma unroll
    for (int r = 0; r < 4; ++r) { best[mt][r] = 3.4e38f; bi[mt][r] = 0; }

  const _Float16* ph = CBh + ((size_t)(cq * 2048 + col) * E + kg * 8);
  const _Float16* pr = CBr + ((size_t)(cq * 2048 + col) * E + kg * 8);
  const float* pc = ccg + cq * 2048 + col;
  int curIdx = cq * 2048 + col;

  for (int tt = 0; tt < 128; ++tt) {
    const half8 bh = *(const half8*)ph;
    const half8 br = *(const half8*)pr;
    const float ccv = *pc;
    ph += 16 * E; pr += 16 * E; pc += 16;
#pragma unroll
    for (int mt = 0; mt < 2; ++mt) {
      f32x4 aM = __builtin_amdgcn_mfma_f32_16x16x32_f16(zh[mt], bh, zero4, 0, 0, 0);
      f32x4 aR = __builtin_amdgcn_mfma_f32_16x16x32_f16(zr[mt], bh, zero4, 0, 0, 0);
      aR = __builtin_amdgcn_mfma_f32_16x16x32_f16(zh[mt], br, aR, 0, 0, 0);
#pragma unroll
      for (int r = 0; r < 4; ++r) {
        const float u = fmaf(aR[r], 2.44140625e-4f, aM[r]);   // dot = accM + accR*2^-12
        const float d = fmaf(u, -2.0f, ccv);                  // cc - 2*dot  (zz dropped)
        if (d < best[mt][r]) { best[mt][r] = d; bi[mt][r] = curIdx; }
      }
    }
    curIdx += 16;
  }

  // butterfly across the 16 code lanes (within each kg group); tie -> lowest index
#pragma unroll
  for (int m = 1; m <= 8; m <<= 1) {
#pragma unroll
    for (int mt = 0; mt < 2; ++mt)
#pragma unroll
      for (int r = 0; r < 4; ++r) {
        const float ob = __shfl_xor(best[mt][r], m, 64);
        const int   oi = __shfl_xor(bi[mt][r],   m, 64);
        if (ob < best[mt][r] || (ob == best[mt][r] && oi < bi[mt][r])) {
          best[mt][r] = ob; bi[mt][r] = oi;
        }
      }
  }

  if (col == 0) {
#pragma unroll
    for (int mt = 0; mt < 2; ++mt)
#pragma unroll
      for (int r = 0; r < 4; ++r) {
        const int rl = mh * 32 + mt * 16 + kg * 4 + r;   // C/D row = kg*4 + reg
        bDs[rl][cq] = best[mt][r];
        bIs[rl][cq] = bi[mt][r];
      }
  }
  __syncthreads();

  // merge quarters + epilogue: 8 threads per row, 4 floats each
  const int rl = t >> 3, part = t & 7;
  float bd = bDs[rl][0];
  int bidx = bIs[rl][0];
#pragma unroll
  for (int q = 1; q < 4; ++q)
    if (bDs[rl][q] < bd) { bd = bDs[rl][q]; bidx = bIs[rl][q]; }

  const int row = rowBase + rl;
  const float4 c4 = *(const float4*)&CB[(size_t)bidx * E + part * 4];
  const float4 z4 = *(const float4*)&Z[(size_t)row * E + part * 4];
  const float dx = c4.x - z4.x, dy = c4.y - z4.y;
  const float dz = c4.z - z4.z, dw = c4.w - z4.w;
  *(float4*)&zq_out[(size_t)row * E + part * 4] =
      make_float4(z4.x + dx, z4.y + dy, z4.z + dz, z4.w + dw);   // STE
  float ls = dx * dx;
  ls += dy * dy; ls += dz * dz; ls += dw * dw;
  ls += __shfl_xor(ls, 1, 8);
  ls += __shfl_xor(ls, 2, 8);
  ls += __shfl_xor(ls, 4, 8);
  if (part == 0) {
    lossp[row] = ls;
    idx_out[row] = (float)bidx;
  }
}

// ---------------- Kernel D: loss = sum(lossp) / (M*E) ----------------
__global__ __launch_bounds__(256) void loss_reduce(const float* __restrict__ lossp, float* __restrict__ out)
{
  float s = 0.f;
  const float4* p = reinterpret_cast<const float4*>(lossp);
  for (int i = threadIdx.x; i < M / 4; i += 256) {
    float4 v = p[i];
    s += v.x + v.y + v.z + v.w;
  }
#pragma unroll
  for (int m = 32; m >= 1; m >>= 1) s += __shfl_xor(s, m, 64);
  __shared__ float red[4];
  if ((threadIdx.x & 63) == 0) red[threadIdx.x >> 6] = s;
  __syncthreads();
  if (threadIdx.x == 0)
    out[0] = (red[0] + red[1] + red[2] + red[3]) * (1.0f / (float)(M * E));
}

extern "C" void kernel_launch(void* const* d_in, const int* in_sizes, int n_in,
                              void* d_out, int out_size, void* d_ws, size_t ws_size,
                              hipStream_t stream)
{
  const float* X  = (const float*)d_in[0];
  const float* W1 = (const float*)d_in[1];
  const float* b1 = (const float*)d_in[2];
  const float* W2 = (const float*)d_in[3];
  const float* b2 = (const float*)d_in[4];
  const float* CB = (const float*)d_in[5];

  float* out  = (float*)d_out;
  float* zq   = out;
  float* loss = out + 524288;
  float* idxf = out + 524289;

  char* ws = (char*)d_ws;
  float* H1 = (float*)ws;                                  // 48 MB
  float* Z  = (float*)(ws + (size_t)M * D * 4);            // 2 MB
  float* cc = Z + (size_t)M * E;                           // 32 KB
  float* lp = cc + K;                                      // 64 KB
  _Float16* W1aT = (_Float16*)(lp + M);                    // 1.125 MB
  _Float16* W1bT = W1aT + (size_t)D * D;                   // 1.125 MB
  _Float16* CBh  = W1bT + (size_t)D * D;                   // 512 KB
  _Float16* CBr  = CBh + (size_t)K * E;                    // 512 KB

  split_w1t<<<dim3(D / 32, D / 32), 256, 0, stream>>>(W1, W1aT, W1bT);
  cb_prep<<<dim3(K / 256), 256, 0, stream>>>(CB, cc, CBh, CBr);
  gemm1_mfma<<<dim3(M / 128, D / 128), 256, 0, stream>>>(X, W1aT, W1bT, b1, H1);
  gemm2_norm<<<dim3(M / 32), 256, 0, stream>>>(H1, W2, b2, Z);
  vq_mfma<<<dim3(M / 64), 512, 0, stream>>>(Z, CB, CBh, CBr, cc, zq, idxf, lp);
  loss_reduce<<<1, 256, 0, stream>>>(lp, loss);
}